// Round 15
// baseline (272.035 us; speedup 1.0000x reference)
//
#include <hip/hip_runtime.h>

#define B_ 4
#define T_ 2048
#define C_ 1024
#define H_ 16
#define DK_ 64
#define BT_ 8192

using u16 = unsigned short;
using u32 = unsigned int;
using u64 = unsigned long long;
typedef __attribute__((ext_vector_type(8))) short short8;
typedef __attribute__((ext_vector_type(4))) float f32x4;
typedef __attribute__((ext_vector_type(16))) float f32x16;
typedef __attribute__((ext_vector_type(4))) u32 u32x4;
typedef __attribute__((ext_vector_type(2))) u32 u32x2;

__device__ __forceinline__ u16 f2bf(float f) {
  u32 u = __builtin_bit_cast(u32, f);
  u32 r = u + 0x7fffu + ((u >> 16) & 1u);
  return (u16)(r >> 16);
}

__device__ __forceinline__ void glds16(void* lds, const void* g) {
  __builtin_amdgcn_global_load_lds(
      (__attribute__((address_space(1))) u32*)g,
      (__attribute__((address_space(3))) u32*)lds, 16, 0, 0);
}

__device__ __forceinline__ u32 cvtpk_bf16(float lo, float hi) {
  u32 r;
  asm("v_cvt_pk_bf16_f32 %0, %1, %2" : "=v"(r) : "v"(lo), "v"(hi));
  return r;
}

// ---------------- fused prep: 7 tensor cvt + mask bitpack, ONE launch -------
// (r7-measured config) Blocks split traffic-proportionally: q/k/v 420 each,
// weights 52 each, mask 580 (int4 loads; chunk-of-256 bit layout).
__device__ __forceinline__ void cvt_range(const float* __restrict__ s,
                                          u16* __restrict__ d, int n,
                                          int rb, int nblk) {
  int i0 = (rb * 256 + (int)threadIdx.x) * 4;
  int stride = nblk * 256 * 4;
  for (int i = i0; i < n; i += stride) {
    float4 v = *(const float4*)(s + i);
    u64 p = (u64)f2bf(v.x) | ((u64)f2bf(v.y) << 16) |
            ((u64)f2bf(v.z) << 32) | ((u64)f2bf(v.w) << 48);
    *(u64*)(d + i) = p;
  }
}

__global__ __launch_bounds__(256) void prep_k(
    const float* __restrict__ q, const float* __restrict__ k,
    const float* __restrict__ v, const float* __restrict__ Wq,
    const float* __restrict__ Wk, const float* __restrict__ Wv,
    const float* __restrict__ Wf, const int* __restrict__ mask,
    u16* __restrict__ qb, u16* __restrict__ kb, u16* __restrict__ vb,
    u16* __restrict__ Wqb, u16* __restrict__ Wkb, u16* __restrict__ Wvb,
    u16* __restrict__ Wfb, u64* __restrict__ mb) {
  const int bid = blockIdx.x;
  if (bid < 1260) {
    const int which = bid / 420, rb = bid % 420;
    const float* s = which == 0 ? q : which == 1 ? k : v;
    u16* d = which == 0 ? qb : which == 1 ? kb : vb;
    cvt_range(s, d, BT_ * C_, rb, 420);
  } else if (bid < 1468) {
    const int which = (bid - 1260) / 52, rb = (bid - 1260) % 52;
    const float* s = which == 0 ? Wq : which == 1 ? Wk : which == 2 ? Wv : Wf;
    u16* d = which == 0 ? Wqb : which == 1 ? Wkb : which == 2 ? Wvb : Wfb;
    cvt_range(s, d, C_ * C_, rb, 52);
  } else {
    const int nch = B_ * T_ * T_ / 256;
    const int lane = threadIdx.x & 63;
    int g0 = (bid - 1468) * 16 + ((int)threadIdx.x >> 6) * 4;
    for (int g = g0; g < nch; g += 580 * 16) {
#pragma unroll
      for (int gg = 0; gg < 4; ++gg) {
        const int4 vv = *(const int4*)(mask + (size_t)(g + gg) * 256 + 4 * lane);
        const u64 b0 = __ballot(vv.x != 0);
        const u64 b1 = __ballot(vv.y != 0);
        const u64 b2 = __ballot(vv.z != 0);
        const u64 b3 = __ballot(vv.w != 0);
        const u64 wv = lane == 0 ? b0 : lane == 1 ? b1 : lane == 2 ? b2 : b3;
        if (lane < 4) mb[(size_t)(g + gg) * 4 + lane] = wv;
      }
    }
  }
}

// ---------------- NT GEMM, 128x128 tile, bf16 MFMA (m97 structure) ----------
template <int MODE>
__global__ __launch_bounds__(256) void gemm_nt(
    const u16* __restrict__ A, const u16* __restrict__ Bmat,
    const float* __restrict__ bias, void* __restrict__ out,
    int M, int N, int K, float scale) {
  __shared__ __align__(16) u16 As[128 * 32];
  __shared__ __align__(16) u16 Bs[128 * 32];
  const int t = threadIdx.x;
  const int lane = t & 63;
  const int wave = t >> 6;
  const int wr = wave >> 1, wc = wave & 1;
  const int lr = lane & 15, lg = lane >> 4;
  const int m0 = blockIdx.x * 128;
  const int n0 = blockIdx.y * 128;

  f32x4 acc[4][4] = {};

  const int srow = t >> 2;
  const int scol = (t & 3) * 8;
  const u16* ag = A + (size_t)(m0 + srow) * K + scol;
  const u16* bg = Bmat + (size_t)(n0 + srow) * K + scol;
  u16* as0 = &As[srow * 32 + scol];
  u16* as1 = &As[(srow + 64) * 32 + scol];
  u16* bs0 = &Bs[srow * 32 + scol];
  u16* bs1 = &Bs[(srow + 64) * 32 + scol];

  for (int k0 = 0; k0 < K; k0 += 32) {
    glds16(as0, ag + k0);
    glds16(as1, ag + (size_t)64 * K + k0);
    glds16(bs0, bg + k0);
    glds16(bs1, bg + (size_t)64 * K + k0);
    __syncthreads();
    short8 af[4], bf[4];
#pragma unroll
    for (int m = 0; m < 4; ++m)
      af[m] = *(const short8*)&As[(wr * 64 + m * 16 + lr) * 32 + lg * 8];
#pragma unroll
    for (int n = 0; n < 4; ++n)
      bf[n] = *(const short8*)&Bs[(wc * 64 + n * 16 + lr) * 32 + lg * 8];
#pragma unroll
    for (int m = 0; m < 4; ++m)
#pragma unroll
      for (int n = 0; n < 4; ++n)
        acc[m][n] = __builtin_amdgcn_mfma_f32_16x16x32_bf16(af[m], bf[n], acc[m][n], 0, 0, 0);
    __syncthreads();
  }

#pragma unroll
  for (int m = 0; m < 4; ++m) {
#pragma unroll
    for (int n = 0; n < 4; ++n) {
#pragma unroll
      for (int j = 0; j < 4; ++j) {
        const int gm = m0 + wr * 64 + m * 16 + lg * 4 + j;
        const int gn = n0 + wc * 64 + n * 16 + lr;
        float v = acc[m][n][j];
        if (MODE == 0) {
          v = (v + bias[gn]) * scale;
          const int b = gm >> 11, tt = gm & 2047, h = gn >> 6, d = gn & 63;
          ((u16*)out)[((((size_t)b * H_ + h) * T_ + tt) << 6) + d] = f2bf(v);
        } else if (MODE == 1) {
          // V^T path: permute token index (swap bits 2<->3) so attn's PV
          // fragment is one contiguous 16B LDS read.
          v += bias[gm];
          const int gnp = (gn & ~12) | ((gn & 4) << 1) | ((gn & 8) >> 1);
          ((u16*)out)[(size_t)gm * N + gnp] = f2bf(v);
        } else {
          v += bias[gn];
          ((float*)out)[(size_t)gm * N + gn] = v;
        }
      }
    }
  }
}

// ---------------- masked flash attention (r13 config + mask-hoist) ----------
// Qh: [B,H,T,64] bf16 pre-scaled by 0.125*log2(e).  Kh: [B,H,T,64] bf16.
// Vt: [H*64][B*T] bf16, token index bit2<->bit3 permuted.  mb: bitmask
// (chunk-of-256 layout).  Y: [B,T,C] bf16.
// 8 waves/block, 256 q-rows.  KVBLK=128 (2 sub-tiles, ONE barrier per 128 kv).
// LDS pitches 68/132 u16 (2-bank/row rotation -> conflict-free paired b64).
// No-max softmax: p = exp2(s) & maskbit; l via ones-column MFMA.
// Mask words hoisted to once per 128-kv iter (both sub-tiles share the same
// 256-entry chunk); per-bit sext via v_bfe_i32.
__global__ __launch_bounds__(512) void attn32_k(
    const u16* __restrict__ Qh, const u16* __restrict__ Kh,
    const u16* __restrict__ Vt, const u64* __restrict__ mb,
    u16* __restrict__ Y) {
  __shared__ __align__(16) u16 Ks[2][128 * 68];
  __shared__ __align__(16) u16 Vs[2][64 * 132];

  // XCD-bijective remap: 512 blocks, 64 consecutive logical ids per XCD
  const int f = blockIdx.x;
  const int lgid = ((f & 7) << 6) | (f >> 3);
  const int bh = lgid >> 3, qblk = lgid & 7;
  const int b = bh >> 4, h = bh & 15;
  const int t = threadIdx.x;
  const int wave = t >> 6, lane = t & 63;
  const int lq = lane & 31, hi = lane >> 5;
  const int q0 = qblk * 256 + wave * 32;

  // Q B-fragments: lane holds Q[q0+lq][kt*16 + 8*hi .. +7]
  const u16* Qp = Qh + ((size_t)bh * T_ + q0 + lq) * DK_ + hi * 8;
  short8 qf[4];
#pragma unroll
  for (int kt = 0; kt < 4; ++kt) qf[kt] = *(const short8*)(Qp + kt * 16);

  const u16* KgB = Kh + (size_t)bh * T_ * DK_;
  const u16* VtB = Vt + (size_t)h * DK_ * BT_ + (size_t)b * T_;
  const u64* mrow = mb + ((size_t)b * T_ + q0 + lq) * (T_ / 64);

  // staging maps: K tile 128x64 (1024 16B chunks), V tile 64x128 (1024 chunks)
  const int kr = t >> 3, ku = t & 7;       // K chunks t and t+512 (rows +64)
  const u16* ksrcA = KgB + (size_t)kr * DK_ + ku * 8;
  const u16* ksrcB = KgB + (size_t)(kr + 64) * DK_ + ku * 8;
  const int kdstA = kr * 68 + ku * 8, kdstB = (kr + 64) * 68 + ku * 8;
  const int vr = t >> 4, vu = t & 15;      // V chunks t and t+512 (rows +32)
  const u16* vsrcA = VtB + (size_t)vr * BT_ + vu * 8;
  const u16* vsrcB = VtB + (size_t)(vr + 32) * BT_ + vu * 8;
  const int vdstA = vr * 132 + vu * 8, vdstB = (vr + 32) * 132 + vu * 8;

  const u32x4 onesu = {0x3F803F80u, 0x3F803F80u, 0x3F803F80u, 0x3F803F80u};
  const short8 ones8 = __builtin_bit_cast(short8, onesu);

  f32x16 o0 = {}, o1 = {}, accl = {};

  // prologue: stage tile 0
  u32x4 kpA = *(const u32x4*)(ksrcA), kpB = *(const u32x4*)(ksrcB);
  u32x4 vpA = *(const u32x4*)(vsrcA), vpB = *(const u32x4*)(vsrcB);
  *(u32x2*)&Ks[0][kdstA] = (u32x2){kpA[0], kpA[1]};
  *(u32x2*)&Ks[0][kdstA + 4] = (u32x2){kpA[2], kpA[3]};
  *(u32x2*)&Ks[0][kdstB] = (u32x2){kpB[0], kpB[1]};
  *(u32x2*)&Ks[0][kdstB + 4] = (u32x2){kpB[2], kpB[3]};
  *(u32x2*)&Vs[0][vdstA] = (u32x2){vpA[0], vpA[1]};
  *(u32x2*)&Vs[0][vdstA + 4] = (u32x2){vpA[2], vpA[3]};
  *(u32x2*)&Vs[0][vdstB] = (u32x2){vpB[0], vpB[1]};
  *(u32x2*)&Vs[0][vdstB + 4] = (u32x2){vpB[2], vpB[3]};
  __syncthreads();
  int cur = 0;

  for (int kv = 0; kv < T_; kv += 128) {
    const bool pre = (kv + 128) < T_;

    // hoisted mask words for this 128-kv iter (shared by both sub-tiles);
    // pre-shift by sh0 so s2=0 extract = low 16 bits, s2=1 = >>16.
    const u64* wp = mrow + ((kv >> 8) << 2);
    const int sh0 = ((kv >> 2) & 48) + hi;
    u64 msh[4];
#pragma unroll
    for (int e = 0; e < 4; ++e) msh[e] = wp[e] >> sh0;

    if (pre) {  // issue next-tile global loads early (T14)
      kpA = *(const u32x4*)(ksrcA + (size_t)(kv + 128) * DK_);
      kpB = *(const u32x4*)(ksrcB + (size_t)(kv + 128) * DK_);
      vpA = *(const u32x4*)(vsrcA + (kv + 128));
      vpB = *(const u32x4*)(vsrcB + (kv + 128));
    }

#pragma unroll
    for (int s2 = 0; s2 < 2; ++s2) {
      // S^T = K * Q^T from LDS (paired b64 reads, conflict-free)
      f32x16 c0 = {}, c1 = {};
      __builtin_amdgcn_s_setprio(1);
#pragma unroll
      for (int kt = 0; kt < 4; ++kt) {
        const int ix = (2 * kt + hi) * 8;
        const u32x2 a0 = *(const u32x2*)&Ks[cur][(64 * s2 + lq) * 68 + ix];
        const u32x2 a1 = *(const u32x2*)&Ks[cur][(64 * s2 + lq) * 68 + ix + 4];
        const u32x2 b0 = *(const u32x2*)&Ks[cur][(64 * s2 + lq + 32) * 68 + ix];
        const u32x2 b1 = *(const u32x2*)&Ks[cur][(64 * s2 + lq + 32) * 68 + ix + 4];
        const u32x4 k0u = {a0[0], a0[1], a1[0], a1[1]};
        const u32x4 k1u = {b0[0], b0[1], b1[0], b1[1]};
        c0 = __builtin_amdgcn_mfma_f32_32x32x16_bf16(
            __builtin_bit_cast(short8, k0u), qf[kt], c0, 0, 0, 0);
        c1 = __builtin_amdgcn_mfma_f32_32x32x16_bf16(
            __builtin_bit_cast(short8, k1u), qf[kt], c1, 0, 0, 0);
      }
      __builtin_amdgcn_s_setprio(0);

      // p = exp2(s) AND maskbit (bit sext via v_bfe_i32)
      u32 tp[4];
#pragma unroll
      for (int e = 0; e < 4; ++e)
        tp[e] = s2 ? (u32)(msh[e] >> 16) : (u32)msh[e];
#pragma unroll
      for (int r = 0; r < 16; ++r) {
        const int pp = 2 * (r >> 2);
        const u32 k0m = (u32)__builtin_amdgcn_sbfe((int)tp[r & 3], pp, 1);
        const u32 k1m = (u32)__builtin_amdgcn_sbfe((int)tp[r & 3], pp + 8, 1);
        c0[r] = __builtin_bit_cast(
            float, __builtin_bit_cast(u32, __builtin_amdgcn_exp2f(c0[r])) & k0m);
        c1[r] = __builtin_bit_cast(
            float, __builtin_bit_cast(u32, __builtin_amdgcn_exp2f(c1[r])) & k1m);
      }

      // P -> bf16 PV A-fragments, IN-LANE pack (relabeled contraction sigma)
      u32 pw_[4][4];
#pragma unroll
      for (int g = 0; g < 4; ++g) {
        const int ob = (g & 1) * 8;
#pragma unroll
        for (int w2 = 0; w2 < 4; ++w2) {
          const float lo = (g < 2) ? c0[ob + 2 * w2] : c1[ob + 2 * w2];
          const float hii = (g < 2) ? c0[ob + 2 * w2 + 1] : c1[ob + 2 * w2 + 1];
          pw_[g][w2] = cvtpk_bf16(lo, hii);
        }
      }

      // PV + row-sum l (ones-column MFMA)
      __builtin_amdgcn_s_setprio(1);
#pragma unroll
      for (int g = 0; g < 4; ++g) {
        const int ix = 16 * (4 * s2 + g) + 8 * hi;
        const u32x2 va = *(const u32x2*)&Vs[cur][lq * 132 + ix];
        const u32x2 vb = *(const u32x2*)&Vs[cur][lq * 132 + ix + 4];
        const u32x2 wa = *(const u32x2*)&Vs[cur][(lq + 32) * 132 + ix];
        const u32x2 wb = *(const u32x2*)&Vs[cur][(lq + 32) * 132 + ix + 4];
        const u32x4 pu = {pw_[g][0], pw_[g][1], pw_[g][2], pw_[g][3]};
        const u32x4 v0u = {va[0], va[1], vb[0], vb[1]};
        const u32x4 v1u = {wa[0], wa[1], wb[0], wb[1]};
        const short8 pa = __builtin_bit_cast(short8, pu);
        o0 = __builtin_amdgcn_mfma_f32_32x32x16_bf16(
            pa, __builtin_bit_cast(short8, v0u), o0, 0, 0, 0);
        o1 = __builtin_amdgcn_mfma_f32_32x32x16_bf16(
            pa, __builtin_bit_cast(short8, v1u), o1, 0, 0, 0);
        accl = __builtin_amdgcn_mfma_f32_32x32x16_bf16(pa, ones8, accl, 0, 0, 0);
      }
      __builtin_amdgcn_s_setprio(0);
    }

    if (pre) {  // write next tile (global loads have landed by now)
      *(u32x2*)&Ks[cur ^ 1][kdstA] = (u32x2){kpA[0], kpA[1]};
      *(u32x2*)&Ks[cur ^ 1][kdstA + 4] = (u32x2){kpA[2], kpA[3]};
      *(u32x2*)&Ks[cur ^ 1][kdstB] = (u32x2){kpB[0], kpB[1]};
      *(u32x2*)&Ks[cur ^ 1][kdstB + 4] = (u32x2){kpB[2], kpB[3]};
      *(u32x2*)&Vs[cur ^ 1][vdstA] = (u32x2){vpA[0], vpA[1]};
      *(u32x2*)&Vs[cur ^ 1][vdstA + 4] = (u32x2){vpA[2], vpA[3]};
      *(u32x2*)&Vs[cur ^ 1][vdstB] = (u32x2){vpB[0], vpB[1]};
      *(u32x2*)&Vs[cur ^ 1][vdstB + 4] = (u32x2){vpB[2], vpB[3]};
    }
    __syncthreads();
    cur ^= 1;
  }

#pragma unroll
  for (int r = 0; r < 16; ++r) {
    const int row = (r & 3) + 8 * (r >> 2) + 4 * hi;
    const float li = 1.0f / accl[r];
    u16* yp = Y + ((size_t)b * T_ + q0 + row) * C_ + h * DK_ + lq;
    yp[0] = f2bf(o0[r] * li);
    yp[32] = f2bf(o1[r] * li);
  }
}

// ---------------------------------------------------------------------------
extern "C" void kernel_launch(void* const* d_in, const int* in_sizes, int n_in,
                              void* d_out, int out_size, void* d_ws, size_t ws_size,
                              hipStream_t stream) {
  const float* q  = (const float*)d_in[0];
  const float* k  = (const float*)d_in[1];
  const float* v  = (const float*)d_in[2];
  const int* mask = (const int*)d_in[3];
  const float* Wq = (const float*)d_in[4];
  const float* bq = (const float*)d_in[5];
  const float* Wk = (const float*)d_in[6];
  const float* bk = (const float*)d_in[7];
  const float* Wv = (const float*)d_in[8];
  const float* bv = (const float*)d_in[9];
  const float* Wf = (const float*)d_in[10];
  const float* bf = (const float*)d_in[11];
  float* out = (float*)d_out;
  char* ws = (char*)d_ws;

  size_t off = 0;
  auto nxt = [&](size_t bytes) -> void* {
    void* p = ws + off;
    off += (bytes + 255) & ~(size_t)255;
    return p;
  };
  const size_t big = (size_t)BT_ * C_ * 2;   // 16 MB
  const size_t wsz = (size_t)C_ * C_ * 2;    // 2 MB
  u16* qb  = (u16*)nxt(big);
  u16* kb  = (u16*)nxt(big);
  u16* vb  = (u16*)nxt(big);
  u16* Wqb = (u16*)nxt(wsz);
  u16* Wkb = (u16*)nxt(wsz);
  u16* Wvb = (u16*)nxt(wsz);
  u16* Wfb = (u16*)nxt(wsz);
  u16* Qh  = (u16*)nxt(big);
  u16* Kh  = (u16*)nxt(big);
  u16* Vt  = (u16*)nxt(big);
  u16* Yb  = (u16*)nxt(big);
  u64* mb  = (u64*)nxt((size_t)B_ * T_ * (T_ / 64) * 8);

  // fused conversions + mask bitpack (one launch, traffic-balanced)
  prep_k<<<2048, 256, 0, stream>>>(q, k, v, Wq, Wk, Wv, Wf, mask,
                                   qb, kb, vb, Wqb, Wkb, Wvb, Wfb, mb);

  // projections: Q (scaled by 1/sqrt(dk)*log2e, folded into attention), K
  const float qscale = 0.125f * 1.4426950408889634f;
  gemm_nt<0><<<dim3(BT_ / 128, C_ / 128), 256, 0, stream>>>(qb, Wqb, bq, Qh, BT_, C_, C_, qscale);
  gemm_nt<0><<<dim3(BT_ / 128, C_ / 128), 256, 0, stream>>>(kb, Wkb, bk, Kh, BT_, C_, C_, 1.0f);
  // V transposed + token-permuted: Vt[h*64+d][perm(b*T+t)]
  gemm_nt<1><<<dim3(C_ / 128, BT_ / 128), 256, 0, stream>>>(Wvb, vb, bv, Vt, C_, BT_, C_, 1.0f);

  // attention: 512 blocks x 512 threads (r13 config + mask hoist)
  attn32_k<<<B_ * H_ * (T_ / 256), 512, 0, stream>>>(Qh, Kh, Vt, mb, Yb);

  // output projection -> f32 d_out
  gemm_nt<2><<<dim3(BT_ / 128, C_ / 128), 256, 0, stream>>>(Yb, Wfb, bf, out, BT_, C_, C_, 1.0f);
}

// Round 16
// 263.164 us; speedup vs baseline: 1.0337x; 1.0337x over previous
//
#include <hip/hip_runtime.h>

#define B_ 4
#define T_ 2048
#define C_ 1024
#define H_ 16
#define DK_ 64
#define BT_ 8192

using u16 = unsigned short;
using u32 = unsigned int;
using u64 = unsigned long long;
typedef __attribute__((ext_vector_type(8))) short short8;
typedef __attribute__((ext_vector_type(4))) float f32x4;
typedef __attribute__((ext_vector_type(16))) float f32x16;
typedef __attribute__((ext_vector_type(4))) u32 u32x4;
typedef __attribute__((ext_vector_type(2))) u32 u32x2;

__device__ __forceinline__ u16 f2bf(float f) {
  u32 u = __builtin_bit_cast(u32, f);
  u32 r = u + 0x7fffu + ((u >> 16) & 1u);
  return (u16)(r >> 16);
}

__device__ __forceinline__ void glds16(void* lds, const void* g) {
  __builtin_amdgcn_global_load_lds(
      (__attribute__((address_space(1))) u32*)g,
      (__attribute__((address_space(3))) u32*)lds, 16, 0, 0);
}

__device__ __forceinline__ u32 cvtpk_bf16(float lo, float hi) {
  u32 r;
  asm("v_cvt_pk_bf16_f32 %0, %1, %2" : "=v"(r) : "v"(lo), "v"(hi));
  return r;
}

// ---------------- fused prep: 7 tensor cvt + mask bitpack, ONE launch -------
// (r7-measured config) Blocks split traffic-proportionally: q/k/v 420 each,
// weights 52 each, mask 580 (int4 loads; chunk-of-256 bit layout).
__device__ __forceinline__ void cvt_range(const float* __restrict__ s,
                                          u16* __restrict__ d, int n,
                                          int rb, int nblk) {
  int i0 = (rb * 256 + (int)threadIdx.x) * 4;
  int stride = nblk * 256 * 4;
  for (int i = i0; i < n; i += stride) {
    float4 v = *(const float4*)(s + i);
    u64 p = (u64)f2bf(v.x) | ((u64)f2bf(v.y) << 16) |
            ((u64)f2bf(v.z) << 32) | ((u64)f2bf(v.w) << 48);
    *(u64*)(d + i) = p;
  }
}

__global__ __launch_bounds__(256) void prep_k(
    const float* __restrict__ q, const float* __restrict__ k,
    const float* __restrict__ v, const float* __restrict__ Wq,
    const float* __restrict__ Wk, const float* __restrict__ Wv,
    const float* __restrict__ Wf, const int* __restrict__ mask,
    u16* __restrict__ qb, u16* __restrict__ kb, u16* __restrict__ vb,
    u16* __restrict__ Wqb, u16* __restrict__ Wkb, u16* __restrict__ Wvb,
    u16* __restrict__ Wfb, u64* __restrict__ mb) {
  const int bid = blockIdx.x;
  if (bid < 1260) {
    const int which = bid / 420, rb = bid % 420;
    const float* s = which == 0 ? q : which == 1 ? k : v;
    u16* d = which == 0 ? qb : which == 1 ? kb : vb;
    cvt_range(s, d, BT_ * C_, rb, 420);
  } else if (bid < 1468) {
    const int which = (bid - 1260) / 52, rb = (bid - 1260) % 52;
    const float* s = which == 0 ? Wq : which == 1 ? Wk : which == 2 ? Wv : Wf;
    u16* d = which == 0 ? Wqb : which == 1 ? Wkb : which == 2 ? Wvb : Wfb;
    cvt_range(s, d, C_ * C_, rb, 52);
  } else {
    const int nch = B_ * T_ * T_ / 256;
    const int lane = threadIdx.x & 63;
    int g0 = (bid - 1468) * 16 + ((int)threadIdx.x >> 6) * 4;
    for (int g = g0; g < nch; g += 580 * 16) {
#pragma unroll
      for (int gg = 0; gg < 4; ++gg) {
        const int4 vv = *(const int4*)(mask + (size_t)(g + gg) * 256 + 4 * lane);
        const u64 b0 = __ballot(vv.x != 0);
        const u64 b1 = __ballot(vv.y != 0);
        const u64 b2 = __ballot(vv.z != 0);
        const u64 b3 = __ballot(vv.w != 0);
        const u64 wv = lane == 0 ? b0 : lane == 1 ? b1 : lane == 2 ? b2 : b3;
        if (lane < 4) mb[(size_t)(g + gg) * 4 + lane] = wv;
      }
    }
  }
}

// ---------------- NT GEMM, 128x128 tile, bf16 MFMA (m97 structure) ----------
template <int MODE>
__global__ __launch_bounds__(256) void gemm_nt(
    const u16* __restrict__ A, const u16* __restrict__ Bmat,
    const float* __restrict__ bias, void* __restrict__ out,
    int M, int N, int K, float scale) {
  __shared__ __align__(16) u16 As[128 * 32];
  __shared__ __align__(16) u16 Bs[128 * 32];
  const int t = threadIdx.x;
  const int lane = t & 63;
  const int wave = t >> 6;
  const int wr = wave >> 1, wc = wave & 1;
  const int lr = lane & 15, lg = lane >> 4;
  const int m0 = blockIdx.x * 128;
  const int n0 = blockIdx.y * 128;

  f32x4 acc[4][4] = {};

  const int srow = t >> 2;
  const int scol = (t & 3) * 8;
  const u16* ag = A + (size_t)(m0 + srow) * K + scol;
  const u16* bg = Bmat + (size_t)(n0 + srow) * K + scol;
  u16* as0 = &As[srow * 32 + scol];
  u16* as1 = &As[(srow + 64) * 32 + scol];
  u16* bs0 = &Bs[srow * 32 + scol];
  u16* bs1 = &Bs[(srow + 64) * 32 + scol];

  for (int k0 = 0; k0 < K; k0 += 32) {
    glds16(as0, ag + k0);
    glds16(as1, ag + (size_t)64 * K + k0);
    glds16(bs0, bg + k0);
    glds16(bs1, bg + (size_t)64 * K + k0);
    __syncthreads();
    short8 af[4], bf[4];
#pragma unroll
    for (int m = 0; m < 4; ++m)
      af[m] = *(const short8*)&As[(wr * 64 + m * 16 + lr) * 32 + lg * 8];
#pragma unroll
    for (int n = 0; n < 4; ++n)
      bf[n] = *(const short8*)&Bs[(wc * 64 + n * 16 + lr) * 32 + lg * 8];
#pragma unroll
    for (int m = 0; m < 4; ++m)
#pragma unroll
      for (int n = 0; n < 4; ++n)
        acc[m][n] = __builtin_amdgcn_mfma_f32_16x16x32_bf16(af[m], bf[n], acc[m][n], 0, 0, 0);
    __syncthreads();
  }

#pragma unroll
  for (int m = 0; m < 4; ++m) {
#pragma unroll
    for (int n = 0; n < 4; ++n) {
#pragma unroll
      for (int j = 0; j < 4; ++j) {
        const int gm = m0 + wr * 64 + m * 16 + lg * 4 + j;
        const int gn = n0 + wc * 64 + n * 16 + lr;
        float v = acc[m][n][j];
        if (MODE == 0) {
          v = (v + bias[gn]) * scale;
          const int b = gm >> 11, tt = gm & 2047, h = gn >> 6, d = gn & 63;
          ((u16*)out)[((((size_t)b * H_ + h) * T_ + tt) << 6) + d] = f2bf(v);
        } else if (MODE == 1) {
          // V^T path: permute token index (swap bits 2<->3) so attn's PV
          // fragment is one contiguous 16B LDS read.
          v += bias[gm];
          const int gnp = (gn & ~12) | ((gn & 4) << 1) | ((gn & 8) >> 1);
          ((u16*)out)[(size_t)gm * N + gnp] = f2bf(v);
        } else {
          v += bias[gn];
          ((float*)out)[(size_t)gm * N + gn] = v;
        }
      }
    }
  }
}

// ---------------- masked flash attention (r8/r13-measured config) -----------
// Qh: [B,H,T,64] bf16 pre-scaled by 0.125*log2(e).  Kh: [B,H,T,64] bf16.
// Vt: [H*64][B*T] bf16, token index bit2<->bit3 permuted.  mb: bitmask
// (chunk-of-256 layout).  Y: [B,T,C] bf16.
// 8 waves/block, 256 q-rows.  KVBLK=128 (2 sub-tiles, ONE barrier per 128 kv).
// LDS pitches 68/132 u16 (2-bank/row rotation -> conflict-free paired b64).
// No-max softmax: p = exp2(s) & maskbit; l via ones-column MFMA.
__global__ __launch_bounds__(512) void attn32_k(
    const u16* __restrict__ Qh, const u16* __restrict__ Kh,
    const u16* __restrict__ Vt, const u64* __restrict__ mb,
    u16* __restrict__ Y) {
  __shared__ __align__(16) u16 Ks[2][128 * 68];
  __shared__ __align__(16) u16 Vs[2][64 * 132];

  // XCD-bijective remap: 512 blocks, 64 consecutive logical ids per XCD
  const int f = blockIdx.x;
  const int lgid = ((f & 7) << 6) | (f >> 3);
  const int bh = lgid >> 3, qblk = lgid & 7;
  const int b = bh >> 4, h = bh & 15;
  const int t = threadIdx.x;
  const int wave = t >> 6, lane = t & 63;
  const int lq = lane & 31, hi = lane >> 5;
  const int q0 = qblk * 256 + wave * 32;

  // Q B-fragments: lane holds Q[q0+lq][kt*16 + 8*hi .. +7]
  const u16* Qp = Qh + ((size_t)bh * T_ + q0 + lq) * DK_ + hi * 8;
  short8 qf[4];
#pragma unroll
  for (int kt = 0; kt < 4; ++kt) qf[kt] = *(const short8*)(Qp + kt * 16);

  const u16* KgB = Kh + (size_t)bh * T_ * DK_;
  const u16* VtB = Vt + (size_t)h * DK_ * BT_ + (size_t)b * T_;
  const u64* mrow = mb + ((size_t)b * T_ + q0 + lq) * (T_ / 64);

  // staging maps: K tile 128x64 (1024 16B chunks), V tile 64x128 (1024 chunks)
  const int kr = t >> 3, ku = t & 7;       // K chunks t and t+512 (rows +64)
  const u16* ksrcA = KgB + (size_t)kr * DK_ + ku * 8;
  const u16* ksrcB = KgB + (size_t)(kr + 64) * DK_ + ku * 8;
  const int kdstA = kr * 68 + ku * 8, kdstB = (kr + 64) * 68 + ku * 8;
  const int vr = t >> 4, vu = t & 15;      // V chunks t and t+512 (rows +32)
  const u16* vsrcA = VtB + (size_t)vr * BT_ + vu * 8;
  const u16* vsrcB = VtB + (size_t)(vr + 32) * BT_ + vu * 8;
  const int vdstA = vr * 132 + vu * 8, vdstB = (vr + 32) * 132 + vu * 8;

  const u32x4 onesu = {0x3F803F80u, 0x3F803F80u, 0x3F803F80u, 0x3F803F80u};
  const short8 ones8 = __builtin_bit_cast(short8, onesu);

  f32x16 o0 = {}, o1 = {}, accl = {};

  // prologue: stage tile 0
  u32x4 kpA = *(const u32x4*)(ksrcA), kpB = *(const u32x4*)(ksrcB);
  u32x4 vpA = *(const u32x4*)(vsrcA), vpB = *(const u32x4*)(vsrcB);
  *(u32x2*)&Ks[0][kdstA] = (u32x2){kpA[0], kpA[1]};
  *(u32x2*)&Ks[0][kdstA + 4] = (u32x2){kpA[2], kpA[3]};
  *(u32x2*)&Ks[0][kdstB] = (u32x2){kpB[0], kpB[1]};
  *(u32x2*)&Ks[0][kdstB + 4] = (u32x2){kpB[2], kpB[3]};
  *(u32x2*)&Vs[0][vdstA] = (u32x2){vpA[0], vpA[1]};
  *(u32x2*)&Vs[0][vdstA + 4] = (u32x2){vpA[2], vpA[3]};
  *(u32x2*)&Vs[0][vdstB] = (u32x2){vpB[0], vpB[1]};
  *(u32x2*)&Vs[0][vdstB + 4] = (u32x2){vpB[2], vpB[3]};
  __syncthreads();
  int cur = 0;

  for (int kv = 0; kv < T_; kv += 128) {
    const bool pre = (kv + 128) < T_;
    if (pre) {  // issue next-tile global loads early (T14)
      kpA = *(const u32x4*)(ksrcA + (size_t)(kv + 128) * DK_);
      kpB = *(const u32x4*)(ksrcB + (size_t)(kv + 128) * DK_);
      vpA = *(const u32x4*)(vsrcA + (kv + 128));
      vpB = *(const u32x4*)(vsrcB + (kv + 128));
    }

#pragma unroll
    for (int s2 = 0; s2 < 2; ++s2) {
      const int kvs = kv + 64 * s2;
      // S^T = K * Q^T from LDS (paired b64 reads, conflict-free)
      f32x16 c0 = {}, c1 = {};
      __builtin_amdgcn_s_setprio(1);
#pragma unroll
      for (int kt = 0; kt < 4; ++kt) {
        const int ix = (2 * kt + hi) * 8;
        const u32x2 a0 = *(const u32x2*)&Ks[cur][(64 * s2 + lq) * 68 + ix];
        const u32x2 a1 = *(const u32x2*)&Ks[cur][(64 * s2 + lq) * 68 + ix + 4];
        const u32x2 b0 = *(const u32x2*)&Ks[cur][(64 * s2 + lq + 32) * 68 + ix];
        const u32x2 b1 = *(const u32x2*)&Ks[cur][(64 * s2 + lq + 32) * 68 + ix + 4];
        const u32x4 k0u = {a0[0], a0[1], a1[0], a1[1]};
        const u32x4 k1u = {b0[0], b0[1], b1[0], b1[1]};
        c0 = __builtin_amdgcn_mfma_f32_32x32x16_bf16(
            __builtin_bit_cast(short8, k0u), qf[kt], c0, 0, 0, 0);
        c1 = __builtin_amdgcn_mfma_f32_32x32x16_bf16(
            __builtin_bit_cast(short8, k1u), qf[kt], c1, 0, 0, 0);
      }
      __builtin_amdgcn_s_setprio(0);

      // p = exp2(s) AND maskbit
      const u64* wp = mrow + ((kvs >> 8) << 2);
      const int sh = ((kvs >> 2) & 48) + hi;
      u32 tp[4];
#pragma unroll
      for (int e = 0; e < 4; ++e) tp[e] = (u32)(wp[e] >> sh);
#pragma unroll
      for (int r = 0; r < 16; ++r) {
        const int pp = 2 * (r >> 2);
        const u32 k0m = (u32)(((int)(tp[r & 3] << (31 - pp))) >> 31);
        const u32 k1m = (u32)(((int)(tp[r & 3] << (23 - pp))) >> 31);
        c0[r] = __builtin_bit_cast(
            float, __builtin_bit_cast(u32, __builtin_amdgcn_exp2f(c0[r])) & k0m);
        c1[r] = __builtin_bit_cast(
            float, __builtin_bit_cast(u32, __builtin_amdgcn_exp2f(c1[r])) & k1m);
      }

      // P -> bf16 PV A-fragments, IN-LANE pack (relabeled contraction sigma)
      u32 pw_[4][4];
#pragma unroll
      for (int g = 0; g < 4; ++g) {
        const int ob = (g & 1) * 8;
#pragma unroll
        for (int w2 = 0; w2 < 4; ++w2) {
          const float lo = (g < 2) ? c0[ob + 2 * w2] : c1[ob + 2 * w2];
          const float hii = (g < 2) ? c0[ob + 2 * w2 + 1] : c1[ob + 2 * w2 + 1];
          pw_[g][w2] = cvtpk_bf16(lo, hii);
        }
      }

      // PV + row-sum l (ones-column MFMA)
      __builtin_amdgcn_s_setprio(1);
#pragma unroll
      for (int g = 0; g < 4; ++g) {
        const int ix = 16 * (4 * s2 + g) + 8 * hi;
        const u32x2 va = *(const u32x2*)&Vs[cur][lq * 132 + ix];
        const u32x2 vb = *(const u32x2*)&Vs[cur][lq * 132 + ix + 4];
        const u32x2 wa = *(const u32x2*)&Vs[cur][(lq + 32) * 132 + ix];
        const u32x2 wb = *(const u32x2*)&Vs[cur][(lq + 32) * 132 + ix + 4];
        const u32x4 pu = {pw_[g][0], pw_[g][1], pw_[g][2], pw_[g][3]};
        const u32x4 v0u = {va[0], va[1], vb[0], vb[1]};
        const u32x4 v1u = {wa[0], wa[1], wb[0], wb[1]};
        const short8 pa = __builtin_bit_cast(short8, pu);
        o0 = __builtin_amdgcn_mfma_f32_32x32x16_bf16(
            pa, __builtin_bit_cast(short8, v0u), o0, 0, 0, 0);
        o1 = __builtin_amdgcn_mfma_f32_32x32x16_bf16(
            pa, __builtin_bit_cast(short8, v1u), o1, 0, 0, 0);
        accl = __builtin_amdgcn_mfma_f32_32x32x16_bf16(pa, ones8, accl, 0, 0, 0);
      }
      __builtin_amdgcn_s_setprio(0);
    }

    if (pre) {  // write next tile (global loads have landed by now)
      *(u32x2*)&Ks[cur ^ 1][kdstA] = (u32x2){kpA[0], kpA[1]};
      *(u32x2*)&Ks[cur ^ 1][kdstA + 4] = (u32x2){kpA[2], kpA[3]};
      *(u32x2*)&Ks[cur ^ 1][kdstB] = (u32x2){kpB[0], kpB[1]};
      *(u32x2*)&Ks[cur ^ 1][kdstB + 4] = (u32x2){kpB[2], kpB[3]};
      *(u32x2*)&Vs[cur ^ 1][vdstA] = (u32x2){vpA[0], vpA[1]};
      *(u32x2*)&Vs[cur ^ 1][vdstA + 4] = (u32x2){vpA[2], vpA[3]};
      *(u32x2*)&Vs[cur ^ 1][vdstB] = (u32x2){vpB[0], vpB[1]};
      *(u32x2*)&Vs[cur ^ 1][vdstB + 4] = (u32x2){vpB[2], vpB[3]};
    }
    __syncthreads();
    cur ^= 1;
  }

#pragma unroll
  for (int r = 0; r < 16; ++r) {
    const int row = (r & 3) + 8 * (r >> 2) + 4 * hi;
    const float li = 1.0f / accl[r];
    u16* yp = Y + ((size_t)b * T_ + q0 + row) * C_ + h * DK_ + lq;
    yp[0] = f2bf(o0[r] * li);
    yp[32] = f2bf(o1[r] * li);
  }
}

// ---------------------------------------------------------------------------
extern "C" void kernel_launch(void* const* d_in, const int* in_sizes, int n_in,
                              void* d_out, int out_size, void* d_ws, size_t ws_size,
                              hipStream_t stream) {
  const float* q  = (const float*)d_in[0];
  const float* k  = (const float*)d_in[1];
  const float* v  = (const float*)d_in[2];
  const int* mask = (const int*)d_in[3];
  const float* Wq = (const float*)d_in[4];
  const float* bq = (const float*)d_in[5];
  const float* Wk = (const float*)d_in[6];
  const float* bk = (const float*)d_in[7];
  const float* Wv = (const float*)d_in[8];
  const float* bv = (const float*)d_in[9];
  const float* Wf = (const float*)d_in[10];
  const float* bf = (const float*)d_in[11];
  float* out = (float*)d_out;
  char* ws = (char*)d_ws;

  size_t off = 0;
  auto nxt = [&](size_t bytes) -> void* {
    void* p = ws + off;
    off += (bytes + 255) & ~(size_t)255;
    return p;
  };
  const size_t big = (size_t)BT_ * C_ * 2;   // 16 MB
  const size_t wsz = (size_t)C_ * C_ * 2;    // 2 MB
  u16* qb  = (u16*)nxt(big);
  u16* kb  = (u16*)nxt(big);
  u16* vb  = (u16*)nxt(big);
  u16* Wqb = (u16*)nxt(wsz);
  u16* Wkb = (u16*)nxt(wsz);
  u16* Wvb = (u16*)nxt(wsz);
  u16* Wfb = (u16*)nxt(wsz);
  u16* Qh  = (u16*)nxt(big);
  u16* Kh  = (u16*)nxt(big);
  u16* Vt  = (u16*)nxt(big);
  u16* Yb  = (u16*)nxt(big);
  u64* mb  = (u64*)nxt((size_t)B_ * T_ * (T_ / 64) * 8);

  // fused conversions + mask bitpack (one launch, traffic-balanced)
  prep_k<<<2048, 256, 0, stream>>>(q, k, v, Wq, Wk, Wv, Wf, mask,
                                   qb, kb, vb, Wqb, Wkb, Wvb, Wfb, mb);

  // projections: Q (scaled by 1/sqrt(dk)*log2e, folded into attention), K
  const float qscale = 0.125f * 1.4426950408889634f;
  gemm_nt<0><<<dim3(BT_ / 128, C_ / 128), 256, 0, stream>>>(qb, Wqb, bq, Qh, BT_, C_, C_, qscale);
  gemm_nt<0><<<dim3(BT_ / 128, C_ / 128), 256, 0, stream>>>(kb, Wkb, bk, Kh, BT_, C_, C_, 1.0f);
  // V transposed + token-permuted: Vt[h*64+d][perm(b*T+t)]
  gemm_nt<1><<<dim3(C_ / 128, BT_ / 128), 256, 0, stream>>>(Wvb, vb, bv, Vt, C_, BT_, C_, 1.0f);

  // attention: 512 blocks x 512 threads (r8/r13 config, 111.4 us measured)
  attn32_k<<<B_ * H_ * (T_ / 256), 512, 0, stream>>>(Qh, Kh, Vt, mb, Yb);

  // output projection -> f32 d_out
  gemm_nt<2><<<dim3(BT_ / 128, C_ / 128), 256, 0, stream>>>(Yb, Wfb, bf, out, BT_, C_, C_, 1.0f);
}

// Round 17
// 258.422 us; speedup vs baseline: 1.0527x; 1.0183x over previous
//
#include <hip/hip_runtime.h>

#define B_ 4
#define T_ 2048
#define C_ 1024
#define H_ 16
#define DK_ 64
#define BT_ 8192

using u16 = unsigned short;
using u32 = unsigned int;
using u64 = unsigned long long;
typedef __attribute__((ext_vector_type(8))) short short8;
typedef __attribute__((ext_vector_type(4))) float f32x4;
typedef __attribute__((ext_vector_type(16))) float f32x16;
typedef __attribute__((ext_vector_type(4))) u32 u32x4;
typedef __attribute__((ext_vector_type(2))) u32 u32x2;

__device__ __forceinline__ u16 f2bf(float f) {
  u32 u = __builtin_bit_cast(u32, f);
  u32 r = u + 0x7fffu + ((u >> 16) & 1u);
  return (u16)(r >> 16);
}

__device__ __forceinline__ void glds16(void* lds, const void* g) {
  __builtin_amdgcn_global_load_lds(
      (__attribute__((address_space(1))) u32*)g,
      (__attribute__((address_space(3))) u32*)lds, 16, 0, 0);
}

__device__ __forceinline__ u32 cvtpk_bf16(float lo, float hi) {
  u32 r;
  asm("v_cvt_pk_bf16_f32 %0, %1, %2" : "=v"(r) : "v"(lo), "v"(hi));
  return r;
}

// ---------------- fused prep: 7 tensor cvt + mask bitpack, ONE launch -------
// (r7-measured config) Blocks split traffic-proportionally: q/k/v 420 each,
// weights 52 each, mask 580 (int4 loads; chunk-of-256 bit layout).
__device__ __forceinline__ void cvt_range(const float* __restrict__ s,
                                          u16* __restrict__ d, int n,
                                          int rb, int nblk) {
  int i0 = (rb * 256 + (int)threadIdx.x) * 4;
  int stride = nblk * 256 * 4;
  for (int i = i0; i < n; i += stride) {
    float4 v = *(const float4*)(s + i);
    u64 p = (u64)f2bf(v.x) | ((u64)f2bf(v.y) << 16) |
            ((u64)f2bf(v.z) << 32) | ((u64)f2bf(v.w) << 48);
    *(u64*)(d + i) = p;
  }
}

__global__ __launch_bounds__(256) void prep_k(
    const float* __restrict__ q, const float* __restrict__ k,
    const float* __restrict__ v, const float* __restrict__ Wq,
    const float* __restrict__ Wk, const float* __restrict__ Wv,
    const float* __restrict__ Wf, const int* __restrict__ mask,
    u16* __restrict__ qb, u16* __restrict__ kb, u16* __restrict__ vb,
    u16* __restrict__ Wqb, u16* __restrict__ Wkb, u16* __restrict__ Wvb,
    u16* __restrict__ Wfb, u64* __restrict__ mb) {
  const int bid = blockIdx.x;
  if (bid < 1260) {
    const int which = bid / 420, rb = bid % 420;
    const float* s = which == 0 ? q : which == 1 ? k : v;
    u16* d = which == 0 ? qb : which == 1 ? kb : vb;
    cvt_range(s, d, BT_ * C_, rb, 420);
  } else if (bid < 1468) {
    const int which = (bid - 1260) / 52, rb = (bid - 1260) % 52;
    const float* s = which == 0 ? Wq : which == 1 ? Wk : which == 2 ? Wv : Wf;
    u16* d = which == 0 ? Wqb : which == 1 ? Wkb : which == 2 ? Wvb : Wfb;
    cvt_range(s, d, C_ * C_, rb, 52);
  } else {
    const int nch = B_ * T_ * T_ / 256;
    const int lane = threadIdx.x & 63;
    int g0 = (bid - 1468) * 16 + ((int)threadIdx.x >> 6) * 4;
    for (int g = g0; g < nch; g += 580 * 16) {
#pragma unroll
      for (int gg = 0; gg < 4; ++gg) {
        const int4 vv = *(const int4*)(mask + (size_t)(g + gg) * 256 + 4 * lane);
        const u64 b0 = __ballot(vv.x != 0);
        const u64 b1 = __ballot(vv.y != 0);
        const u64 b2 = __ballot(vv.z != 0);
        const u64 b3 = __ballot(vv.w != 0);
        const u64 wv = lane == 0 ? b0 : lane == 1 ? b1 : lane == 2 ? b2 : b3;
        if (lane < 4) mb[(size_t)(g + gg) * 4 + lane] = wv;
      }
    }
  }
}

// ---------------- NT GEMM, 128x128 tile, bf16 MFMA (m97 structure) ----------
// MODE 0: bf16 head-layout out (bias[n], scale); MODE 1: V^T out (bias[m],
// token-permute); MODE 2: f32 row-major out.  MODE 0 supports gridDim.z=2:
// blockIdx.z selects the {A,bias,out,scale} a/b set (Q and K projections
// merged into one launch; body identical).
template <int MODE>
__global__ __launch_bounds__(256) void gemm_nt(
    const u16* __restrict__ Aa, const u16* __restrict__ Ab,
    const u16* __restrict__ Ba, const u16* __restrict__ Bb,
    const float* __restrict__ biasa, const float* __restrict__ biasb,
    void* __restrict__ outa, void* __restrict__ outb,
    int M, int N, int K, float scalea, float scaleb) {
  __shared__ __align__(16) u16 As[128 * 32];
  __shared__ __align__(16) u16 Bs[128 * 32];
  const u16* A = blockIdx.z ? Ab : Aa;
  const u16* Bmat = blockIdx.z ? Bb : Ba;
  const float* bias = blockIdx.z ? biasb : biasa;
  void* out = blockIdx.z ? outb : outa;
  const float scale = blockIdx.z ? scaleb : scalea;

  const int t = threadIdx.x;
  const int lane = t & 63;
  const int wave = t >> 6;
  const int wr = wave >> 1, wc = wave & 1;
  const int lr = lane & 15, lg = lane >> 4;
  const int m0 = blockIdx.x * 128;
  const int n0 = blockIdx.y * 128;

  f32x4 acc[4][4] = {};

  const int srow = t >> 2;
  const int scol = (t & 3) * 8;
  const u16* ag = A + (size_t)(m0 + srow) * K + scol;
  const u16* bg = Bmat + (size_t)(n0 + srow) * K + scol;
  u16* as0 = &As[srow * 32 + scol];
  u16* as1 = &As[(srow + 64) * 32 + scol];
  u16* bs0 = &Bs[srow * 32 + scol];
  u16* bs1 = &Bs[(srow + 64) * 32 + scol];

  for (int k0 = 0; k0 < K; k0 += 32) {
    glds16(as0, ag + k0);
    glds16(as1, ag + (size_t)64 * K + k0);
    glds16(bs0, bg + k0);
    glds16(bs1, bg + (size_t)64 * K + k0);
    __syncthreads();
    short8 af[4], bf[4];
#pragma unroll
    for (int m = 0; m < 4; ++m)
      af[m] = *(const short8*)&As[(wr * 64 + m * 16 + lr) * 32 + lg * 8];
#pragma unroll
    for (int n = 0; n < 4; ++n)
      bf[n] = *(const short8*)&Bs[(wc * 64 + n * 16 + lr) * 32 + lg * 8];
#pragma unroll
    for (int m = 0; m < 4; ++m)
#pragma unroll
      for (int n = 0; n < 4; ++n)
        acc[m][n] = __builtin_amdgcn_mfma_f32_16x16x32_bf16(af[m], bf[n], acc[m][n], 0, 0, 0);
    __syncthreads();
  }

#pragma unroll
  for (int m = 0; m < 4; ++m) {
#pragma unroll
    for (int n = 0; n < 4; ++n) {
#pragma unroll
      for (int j = 0; j < 4; ++j) {
        const int gm = m0 + wr * 64 + m * 16 + lg * 4 + j;
        const int gn = n0 + wc * 64 + n * 16 + lr;
        float v = acc[m][n][j];
        if (MODE == 0) {
          v = (v + bias[gn]) * scale;
          const int b = gm >> 11, tt = gm & 2047, h = gn >> 6, d = gn & 63;
          ((u16*)out)[((((size_t)b * H_ + h) * T_ + tt) << 6) + d] = f2bf(v);
        } else if (MODE == 1) {
          // V^T path: permute token index (swap bits 2<->3) so attn's PV
          // fragment is one contiguous 16B LDS read.
          v += bias[gm];
          const int gnp = (gn & ~12) | ((gn & 4) << 1) | ((gn & 8) >> 1);
          ((u16*)out)[(size_t)gm * N + gnp] = f2bf(v);
        } else {
          v += bias[gn];
          ((float*)out)[(size_t)gm * N + gn] = v;
        }
      }
    }
  }
}

// ---------------- masked flash attention (r8/r13-measured config) -----------
// Qh: [B,H,T,64] bf16 pre-scaled by 0.125*log2(e).  Kh: [B,H,T,64] bf16.
// Vt: [H*64][B*T] bf16, token index bit2<->bit3 permuted.  mb: bitmask
// (chunk-of-256 layout).  Y: [B,T,C] bf16.
// 8 waves/block, 256 q-rows.  KVBLK=128 (2 sub-tiles, ONE barrier per 128 kv).
// LDS pitches 68/132 u16 (2-bank/row rotation -> conflict-free paired b64).
// No-max softmax: p = exp2(s) & maskbit; l via ones-column MFMA.
__global__ __launch_bounds__(512) void attn32_k(
    const u16* __restrict__ Qh, const u16* __restrict__ Kh,
    const u16* __restrict__ Vt, const u64* __restrict__ mb,
    u16* __restrict__ Y) {
  __shared__ __align__(16) u16 Ks[2][128 * 68];
  __shared__ __align__(16) u16 Vs[2][64 * 132];

  // XCD-bijective remap: 512 blocks, 64 consecutive logical ids per XCD
  const int f = blockIdx.x;
  const int lgid = ((f & 7) << 6) | (f >> 3);
  const int bh = lgid >> 3, qblk = lgid & 7;
  const int b = bh >> 4, h = bh & 15;
  const int t = threadIdx.x;
  const int wave = t >> 6, lane = t & 63;
  const int lq = lane & 31, hi = lane >> 5;
  const int q0 = qblk * 256 + wave * 32;

  // Q B-fragments: lane holds Q[q0+lq][kt*16 + 8*hi .. +7]
  const u16* Qp = Qh + ((size_t)bh * T_ + q0 + lq) * DK_ + hi * 8;
  short8 qf[4];
#pragma unroll
  for (int kt = 0; kt < 4; ++kt) qf[kt] = *(const short8*)(Qp + kt * 16);

  const u16* KgB = Kh + (size_t)bh * T_ * DK_;
  const u16* VtB = Vt + (size_t)h * DK_ * BT_ + (size_t)b * T_;
  const u64* mrow = mb + ((size_t)b * T_ + q0 + lq) * (T_ / 64);

  // staging maps: K tile 128x64 (1024 16B chunks), V tile 64x128 (1024 chunks)
  const int kr = t >> 3, ku = t & 7;       // K chunks t and t+512 (rows +64)
  const u16* ksrcA = KgB + (size_t)kr * DK_ + ku * 8;
  const u16* ksrcB = KgB + (size_t)(kr + 64) * DK_ + ku * 8;
  const int kdstA = kr * 68 + ku * 8, kdstB = (kr + 64) * 68 + ku * 8;
  const int vr = t >> 4, vu = t & 15;      // V chunks t and t+512 (rows +32)
  const u16* vsrcA = VtB + (size_t)vr * BT_ + vu * 8;
  const u16* vsrcB = VtB + (size_t)(vr + 32) * BT_ + vu * 8;
  const int vdstA = vr * 132 + vu * 8, vdstB = (vr + 32) * 132 + vu * 8;

  const u32x4 onesu = {0x3F803F80u, 0x3F803F80u, 0x3F803F80u, 0x3F803F80u};
  const short8 ones8 = __builtin_bit_cast(short8, onesu);

  f32x16 o0 = {}, o1 = {}, accl = {};

  // prologue: stage tile 0
  u32x4 kpA = *(const u32x4*)(ksrcA), kpB = *(const u32x4*)(ksrcB);
  u32x4 vpA = *(const u32x4*)(vsrcA), vpB = *(const u32x4*)(vsrcB);
  *(u32x2*)&Ks[0][kdstA] = (u32x2){kpA[0], kpA[1]};
  *(u32x2*)&Ks[0][kdstA + 4] = (u32x2){kpA[2], kpA[3]};
  *(u32x2*)&Ks[0][kdstB] = (u32x2){kpB[0], kpB[1]};
  *(u32x2*)&Ks[0][kdstB + 4] = (u32x2){kpB[2], kpB[3]};
  *(u32x2*)&Vs[0][vdstA] = (u32x2){vpA[0], vpA[1]};
  *(u32x2*)&Vs[0][vdstA + 4] = (u32x2){vpA[2], vpA[3]};
  *(u32x2*)&Vs[0][vdstB] = (u32x2){vpB[0], vpB[1]};
  *(u32x2*)&Vs[0][vdstB + 4] = (u32x2){vpB[2], vpB[3]};
  __syncthreads();
  int cur = 0;

  for (int kv = 0; kv < T_; kv += 128) {
    const bool pre = (kv + 128) < T_;
    if (pre) {  // issue next-tile global loads early (T14)
      kpA = *(const u32x4*)(ksrcA + (size_t)(kv + 128) * DK_);
      kpB = *(const u32x4*)(ksrcB + (size_t)(kv + 128) * DK_);
      vpA = *(const u32x4*)(vsrcA + (kv + 128));
      vpB = *(const u32x4*)(vsrcB + (kv + 128));
    }

#pragma unroll
    for (int s2 = 0; s2 < 2; ++s2) {
      const int kvs = kv + 64 * s2;
      // S^T = K * Q^T from LDS (paired b64 reads, conflict-free)
      f32x16 c0 = {}, c1 = {};
      __builtin_amdgcn_s_setprio(1);
#pragma unroll
      for (int kt = 0; kt < 4; ++kt) {
        const int ix = (2 * kt + hi) * 8;
        const u32x2 a0 = *(const u32x2*)&Ks[cur][(64 * s2 + lq) * 68 + ix];
        const u32x2 a1 = *(const u32x2*)&Ks[cur][(64 * s2 + lq) * 68 + ix + 4];
        const u32x2 b0 = *(const u32x2*)&Ks[cur][(64 * s2 + lq + 32) * 68 + ix];
        const u32x2 b1 = *(const u32x2*)&Ks[cur][(64 * s2 + lq + 32) * 68 + ix + 4];
        const u32x4 k0u = {a0[0], a0[1], a1[0], a1[1]};
        const u32x4 k1u = {b0[0], b0[1], b1[0], b1[1]};
        c0 = __builtin_amdgcn_mfma_f32_32x32x16_bf16(
            __builtin_bit_cast(short8, k0u), qf[kt], c0, 0, 0, 0);
        c1 = __builtin_amdgcn_mfma_f32_32x32x16_bf16(
            __builtin_bit_cast(short8, k1u), qf[kt], c1, 0, 0, 0);
      }
      __builtin_amdgcn_s_setprio(0);

      // p = exp2(s) AND maskbit
      const u64* wp = mrow + ((kvs >> 8) << 2);
      const int sh = ((kvs >> 2) & 48) + hi;
      u32 tp[4];
#pragma unroll
      for (int e = 0; e < 4; ++e) tp[e] = (u32)(wp[e] >> sh);
#pragma unroll
      for (int r = 0; r < 16; ++r) {
        const int pp = 2 * (r >> 2);
        const u32 k0m = (u32)(((int)(tp[r & 3] << (31 - pp))) >> 31);
        const u32 k1m = (u32)(((int)(tp[r & 3] << (23 - pp))) >> 31);
        c0[r] = __builtin_bit_cast(
            float, __builtin_bit_cast(u32, __builtin_amdgcn_exp2f(c0[r])) & k0m);
        c1[r] = __builtin_bit_cast(
            float, __builtin_bit_cast(u32, __builtin_amdgcn_exp2f(c1[r])) & k1m);
      }

      // P -> bf16 PV A-fragments, IN-LANE pack (relabeled contraction sigma)
      u32 pw_[4][4];
#pragma unroll
      for (int g = 0; g < 4; ++g) {
        const int ob = (g & 1) * 8;
#pragma unroll
        for (int w2 = 0; w2 < 4; ++w2) {
          const float lo = (g < 2) ? c0[ob + 2 * w2] : c1[ob + 2 * w2];
          const float hii = (g < 2) ? c0[ob + 2 * w2 + 1] : c1[ob + 2 * w2 + 1];
          pw_[g][w2] = cvtpk_bf16(lo, hii);
        }
      }

      // PV + row-sum l (ones-column MFMA)
      __builtin_amdgcn_s_setprio(1);
#pragma unroll
      for (int g = 0; g < 4; ++g) {
        const int ix = 16 * (4 * s2 + g) + 8 * hi;
        const u32x2 va = *(const u32x2*)&Vs[cur][lq * 132 + ix];
        const u32x2 vb = *(const u32x2*)&Vs[cur][lq * 132 + ix + 4];
        const u32x2 wa = *(const u32x2*)&Vs[cur][(lq + 32) * 132 + ix];
        const u32x2 wb = *(const u32x2*)&Vs[cur][(lq + 32) * 132 + ix + 4];
        const u32x4 pu = {pw_[g][0], pw_[g][1], pw_[g][2], pw_[g][3]};
        const u32x4 v0u = {va[0], va[1], vb[0], vb[1]};
        const u32x4 v1u = {wa[0], wa[1], wb[0], wb[1]};
        const short8 pa = __builtin_bit_cast(short8, pu);
        o0 = __builtin_amdgcn_mfma_f32_32x32x16_bf16(
            pa, __builtin_bit_cast(short8, v0u), o0, 0, 0, 0);
        o1 = __builtin_amdgcn_mfma_f32_32x32x16_bf16(
            pa, __builtin_bit_cast(short8, v1u), o1, 0, 0, 0);
        accl = __builtin_amdgcn_mfma_f32_32x32x16_bf16(pa, ones8, accl, 0, 0, 0);
      }
      __builtin_amdgcn_s_setprio(0);
    }

    if (pre) {  // write next tile (global loads have landed by now)
      *(u32x2*)&Ks[cur ^ 1][kdstA] = (u32x2){kpA[0], kpA[1]};
      *(u32x2*)&Ks[cur ^ 1][kdstA + 4] = (u32x2){kpA[2], kpA[3]};
      *(u32x2*)&Ks[cur ^ 1][kdstB] = (u32x2){kpB[0], kpB[1]};
      *(u32x2*)&Ks[cur ^ 1][kdstB + 4] = (u32x2){kpB[2], kpB[3]};
      *(u32x2*)&Vs[cur ^ 1][vdstA] = (u32x2){vpA[0], vpA[1]};
      *(u32x2*)&Vs[cur ^ 1][vdstA + 4] = (u32x2){vpA[2], vpA[3]};
      *(u32x2*)&Vs[cur ^ 1][vdstB] = (u32x2){vpB[0], vpB[1]};
      *(u32x2*)&Vs[cur ^ 1][vdstB + 4] = (u32x2){vpB[2], vpB[3]};
    }
    __syncthreads();
    cur ^= 1;
  }

#pragma unroll
  for (int r = 0; r < 16; ++r) {
    const int row = (r & 3) + 8 * (r >> 2) + 4 * hi;
    const float li = 1.0f / accl[r];
    u16* yp = Y + ((size_t)b * T_ + q0 + row) * C_ + h * DK_ + lq;
    yp[0] = f2bf(o0[r] * li);
    yp[32] = f2bf(o1[r] * li);
  }
}

// ---------------------------------------------------------------------------
extern "C" void kernel_launch(void* const* d_in, const int* in_sizes, int n_in,
                              void* d_out, int out_size, void* d_ws, size_t ws_size,
                              hipStream_t stream) {
  const float* q  = (const float*)d_in[0];
  const float* k  = (const float*)d_in[1];
  const float* v  = (const float*)d_in[2];
  const int* mask = (const int*)d_in[3];
  const float* Wq = (const float*)d_in[4];
  const float* bq = (const float*)d_in[5];
  const float* Wk = (const float*)d_in[6];
  const float* bk = (const float*)d_in[7];
  const float* Wv = (const float*)d_in[8];
  const float* bv = (const float*)d_in[9];
  const float* Wf = (const float*)d_in[10];
  const float* bf = (const float*)d_in[11];
  float* out = (float*)d_out;
  char* ws = (char*)d_ws;

  size_t off = 0;
  auto nxt = [&](size_t bytes) -> void* {
    void* p = ws + off;
    off += (bytes + 255) & ~(size_t)255;
    return p;
  };
  const size_t big = (size_t)BT_ * C_ * 2;   // 16 MB
  const size_t wsz = (size_t)C_ * C_ * 2;    // 2 MB
  u16* qb  = (u16*)nxt(big);
  u16* kb  = (u16*)nxt(big);
  u16* vb  = (u16*)nxt(big);
  u16* Wqb = (u16*)nxt(wsz);
  u16* Wkb = (u16*)nxt(wsz);
  u16* Wvb = (u16*)nxt(wsz);
  u16* Wfb = (u16*)nxt(wsz);
  u16* Qh  = (u16*)nxt(big);
  u16* Kh  = (u16*)nxt(big);
  u16* Vt  = (u16*)nxt(big);
  u16* Yb  = (u16*)nxt(big);
  u64* mb  = (u64*)nxt((size_t)B_ * T_ * (T_ / 64) * 8);

  // fused conversions + mask bitpack (one launch, traffic-balanced)
  prep_k<<<2048, 256, 0, stream>>>(q, k, v, Wq, Wk, Wv, Wf, mask,
                                   qb, kb, vb, Wqb, Wkb, Wvb, Wfb, mb);

  // Q + K projections merged into ONE z=2 launch (z=0: Q with folded
  // softmax scale, z=1: K) — identical GEMM body, pointer select only.
  const float qscale = 0.125f * 1.4426950408889634f;
  gemm_nt<0><<<dim3(BT_ / 128, C_ / 128, 2), 256, 0, stream>>>(
      qb, kb, Wqb, Wkb, bq, bk, Qh, Kh, BT_, C_, C_, qscale, 1.0f);
  // V transposed + token-permuted: Vt[h*64+d][perm(b*T+t)]
  gemm_nt<1><<<dim3(C_ / 128, BT_ / 128, 1), 256, 0, stream>>>(
      Wvb, Wvb, vb, vb, bv, bv, Vt, Vt, C_, BT_, C_, 1.0f, 1.0f);

  // attention: 512 blocks x 512 threads (r8/r13 config, 111.4 us measured)
  attn32_k<<<B_ * H_ * (T_ / 256), 512, 0, stream>>>(Qh, Kh, Vt, mb, Yb);

  // output projection -> f32 d_out
  gemm_nt<2><<<dim3(BT_ / 128, C_ / 128, 1), 256, 0, stream>>>(
      Yb, Yb, Wfb, Wfb, bf, bf, out, out, BT_, C_, C_, 1.0f, 1.0f);
}